// Round 2
// baseline (3499.285 us; speedup 1.0000x reference)
//
#include <hip/hip_runtime.h>
#include <hip/hip_bf16.h>

typedef __hip_bfloat16 bf16;

#define N_NODES 50000
#define E_RAW   800000
#define E_TOT   850000      // E_RAW + N self-loops
#define H_HEADS 8
#define F_DIM   256         // H*32 node feature width (both layers)
#define D_HEAD  32

// ---- dtype-agnostic loads: flags[0]=1 -> floats are fp32; flags[1]=1 -> ints are int32
__device__ __forceinline__ float loadF(const void* p, size_t i, int f32) {
    return f32 ? ((const float*)p)[i] : __bfloat162float(((const bf16*)p)[i]);
}
__device__ __forceinline__ int loadI(const void* p, size_t i, int is32) {
    return is32 ? ((const int*)p)[i] : (int)((const long long*)p)[i];
}

// ---- detect input dtypes from data (deterministic; graph-capture safe) ----
__global__ void detect(const void* __restrict__ x, const void* __restrict__ ei,
                       int* __restrict__ flags) {
    int t = threadIdx.x;
    const unsigned short* xs = (const unsigned short*)x;
    int f32 = 0;
    for (int i = t; i < 8192; i += 256) {
        unsigned e = (xs[i] >> 7) & 0xFF;   // bf16 exponent field
        if (e >= 134) f32 = 1;              // |v|>=128 or NaN/Inf: impossible for bf16 N(0,1)
    }
    const int* eii = (const int*)ei;
    int odd = 0;                            // any nonzero odd slot -> int32 node ids
    for (int i = t; i < 1024; i += 256)
        if (eii[2 * i + 1] != 0) odd = 1;
    if (f32) atomicOr(&flags[0], 1);
    if (odd) atomicOr(&flags[1], 1);
}

// ---------------- GEMM: C[M,256] = A[M,K] @ W[K,256], C f32 -------------------
__global__ void gemm16(const void* __restrict__ A, const void* __restrict__ W,
                       float* __restrict__ C, int K, int a_ws,
                       const int* __restrict__ flags) {
    const int f32 = flags[0];
    const int af = a_ws | f32;              // workspace A is always f32
    __shared__ float As[16][17];
    __shared__ float Ws[16][17];
    int tx = threadIdx.x, ty = threadIdx.y;
    int row = blockIdx.x * 16 + ty;         // 50000 = 3125*16
    int col = blockIdx.y * 16 + tx;
    float acc = 0.f;
    for (int kt = 0; kt < K; kt += 16) {
        As[ty][tx] = loadF(A, (size_t)row * K + kt + tx, af);
        Ws[ty][tx] = loadF(W, (size_t)(kt + ty) * F_DIM + col, f32);
        __syncthreads();
#pragma unroll
        for (int k = 0; k < 16; ++k) acc += As[ty][k] * Ws[k][tx];
        __syncthreads();
    }
    C[(size_t)row * F_DIM + col] = acc;
}

// ---------------- per-(edge,head) attention logit -> exp, accumulate denom ----
__global__ void edge_score(const void* __restrict__ ei,
                           const float* __restrict__ xl, const float* __restrict__ xr,
                           const void* __restrict__ att,
                           float* __restrict__ w, float* __restrict__ es,
                           const int* __restrict__ flags) {
    const int f32 = flags[0], is32 = flags[1];
    __shared__ float atts[F_DIM];
    atts[threadIdx.x] = loadF(att, threadIdx.x, f32);   // blockDim == 256 == F_DIM
    __syncthreads();
    int t = blockIdx.x * blockDim.x + threadIdx.x;      // t = e*8 + h
    if (t >= E_TOT * H_HEADS) return;
    int e = t >> 3, h = t & 7;
    int s, d;
    if (e < E_RAW) { s = loadI(ei, e, is32); d = loadI(ei, (size_t)E_RAW + e, is32); }
    else           { s = d = e - E_RAW; }
    const float4* pl = (const float4*)(xl + (size_t)s * F_DIM + h * D_HEAD);
    const float4* pr = (const float4*)(xr + (size_t)d * F_DIM + h * D_HEAD);
    const float*  pa = atts + h * D_HEAD;
    float acc = 0.f;
#pragma unroll
    for (int i = 0; i < 8; ++i) {
        float4 a = pl[i], b = pr[i];
        float z0 = a.x + b.x; z0 = z0 > 0.f ? z0 : 0.2f * z0;
        float z1 = a.y + b.y; z1 = z1 > 0.f ? z1 : 0.2f * z1;
        float z2 = a.z + b.z; z2 = z2 > 0.f ? z2 : 0.2f * z2;
        float z3 = a.w + b.w; z3 = z3 > 0.f ? z3 : 0.2f * z3;
        acc += z0 * pa[4*i] + z1 * pa[4*i+1] + z2 * pa[4*i+2] + z3 * pa[4*i+3];
    }
    float ew = expf(acc);   // no max-subtraction: logits are O(0.3), exp is safe
    w[t] = ew;
    atomicAdd(&es[d * H_HEADS + h], ew);
}

// ---------------- alpha-weighted scatter-add of xl[src] into acc[dst] ---------
__global__ void edge_aggr(const void* __restrict__ ei,
                          const float* __restrict__ xl,
                          const float* __restrict__ w, const float* __restrict__ es,
                          float* __restrict__ acc, const int* __restrict__ flags) {
    const int is32 = flags[1];
    int e = blockIdx.x;
    int c = threadIdx.x;        // 0..255, h = c>>5
    int h = c >> 5;
    int s, d;
    if (e < E_RAW) { s = loadI(ei, e, is32); d = loadI(ei, (size_t)E_RAW + e, is32); }
    else           { s = d = e - E_RAW; }
    float alpha = w[e * H_HEADS + h] / (es[d * H_HEADS + h] + 1e-16f);
    atomicAdd(&acc[(size_t)d * F_DIM + c], alpha * xl[(size_t)s * F_DIM + c]);
}

// ---------------- h1 = ELU(acc + b1) in place ---------------------------------
__global__ void finalize1(float* __restrict__ acc, const void* __restrict__ b,
                          int total, const int* __restrict__ flags) {
    const int f32 = flags[0];
    int i = blockIdx.x * blockDim.x + threadIdx.x;
    if (i >= total) return;
    float v = acc[i] + loadF(b, i & (F_DIM - 1), f32);
    acc[i] = v > 0.f ? v : expm1f(v);
}

// ---------------- out = mean_heads(acc2) + b2, cast to output dtype -----------
__global__ void finalize2(const float* __restrict__ acc, const void* __restrict__ b,
                          void* __restrict__ out, const int* __restrict__ flags) {
    const int f32 = flags[0];
    int i = blockIdx.x * blockDim.x + threadIdx.x;      // n*32 + d
    if (i >= N_NODES * D_HEAD) return;
    int n = i >> 5, d = i & 31;
    float s = 0.f;
#pragma unroll
    for (int h = 0; h < H_HEADS; ++h) s += acc[(size_t)n * F_DIM + h * D_HEAD + d];
    float v = s * 0.125f + loadF(b, d, f32);
    if (f32) ((float*)out)[i] = v;
    else     ((bf16*)out)[i] = __float2bfloat16(v);
}

extern "C" void kernel_launch(void* const* d_in, const int* in_sizes, int n_in,
                              void* d_out, int out_size, void* d_ws, size_t ws_size,
                              hipStream_t stream) {
    const void* x    = d_in[0];
    const void* ei   = d_in[1];
    const void* Wl1  = d_in[2];
    const void* Wr1  = d_in[3];
    const void* att1 = d_in[4];
    const void* b1   = d_in[5];
    const void* Wl2  = d_in[6];
    const void* Wr2  = d_in[7];
    const void* att2 = d_in[8];
    const void* b2   = d_in[9];

    // workspace layout (fp32): flags | xl | xr | acc | w | es
    int*   flags = (int*)d_ws;
    float* base  = (float*)d_ws + 64;                     // keep 256B alignment
    const size_t NF = (size_t)N_NODES * F_DIM;            // 12.8M floats
    float* xl  = base;
    float* xr  = xl + NF;
    float* acc = xr + NF;
    float* w   = acc + NF;                                // per-(edge,head) exp(logit)
    float* es  = w + (size_t)E_TOT * H_HEADS;             // per-(dst,head) denom

    dim3 gblk(16, 16);
    dim3 ggrd(N_NODES / 16, F_DIM / 16);
    const int nsc = E_TOT * H_HEADS;

    (void)hipMemsetAsync(flags, 0, 16, stream);
    detect<<<1, 256, 0, stream>>>(x, ei, flags);

    // ---------- Layer 1 ----------
    gemm16<<<ggrd, gblk, 0, stream>>>(x, Wl1, xl, 128, 0, flags);
    gemm16<<<ggrd, gblk, 0, stream>>>(x, Wr1, xr, 128, 0, flags);
    (void)hipMemsetAsync(es, 0, (size_t)N_NODES * H_HEADS * sizeof(float), stream);
    (void)hipMemsetAsync(acc, 0, NF * sizeof(float), stream);
    edge_score<<<(nsc + 255) / 256, 256, 0, stream>>>(ei, xl, xr, att1, w, es, flags);
    edge_aggr<<<E_TOT, F_DIM, 0, stream>>>(ei, xl, w, es, acc, flags);
    finalize1<<<((int)NF + 255) / 256, 256, 0, stream>>>(acc, b1, (int)NF, flags);

    // ---------- Layer 2 ----------
    gemm16<<<ggrd, gblk, 0, stream>>>(acc, Wl2, xl, 256, 1, flags);
    gemm16<<<ggrd, gblk, 0, stream>>>(acc, Wr2, xr, 256, 1, flags);
    (void)hipMemsetAsync(es, 0, (size_t)N_NODES * H_HEADS * sizeof(float), stream);
    (void)hipMemsetAsync(acc, 0, NF * sizeof(float), stream);
    edge_score<<<(nsc + 255) / 256, 256, 0, stream>>>(ei, xl, xr, att2, w, es, flags);
    edge_aggr<<<E_TOT, F_DIM, 0, stream>>>(ei, xl, w, es, acc, flags);
    finalize2<<<(N_NODES * D_HEAD + 255) / 256, 256, 0, stream>>>(acc, b2, d_out, flags);
}

// Round 3
// 946.277 us; speedup vs baseline: 3.6979x; 3.6979x over previous
//
#include <hip/hip_runtime.h>
#include <hip/hip_bf16.h>

typedef __hip_bfloat16 bf16;
typedef __attribute__((ext_vector_type(8))) short bf16x8;   // 8 bf16 = 4 VGPRs
typedef __attribute__((ext_vector_type(4))) float f32x4;

#define N_NODES 50000
#define E_RAW   800000
#define E_TOT   850000      // E_RAW + N self-loops
#define H_HEADS 8
#define F_DIM   256
#define D_HEAD  32
#define NB_SCAN 196         // ceil(50000/256)

// ---- dtype-agnostic loads: flags[0]=1 -> floats are fp32; flags[1]=1 -> ints are int32
__device__ __forceinline__ float loadF(const void* p, size_t i, int f32) {
    return f32 ? ((const float*)p)[i] : __bfloat162float(((const bf16*)p)[i]);
}
__device__ __forceinline__ int loadI(const void* p, size_t i, int is32) {
    return is32 ? ((const int*)p)[i] : (int)((const long long*)p)[i];
}

// ---- detect input dtypes from data (deterministic; graph-capture safe) ----
__global__ void detect(const void* __restrict__ x, const void* __restrict__ ei,
                       int* __restrict__ flags) {
    int t = threadIdx.x;
    const unsigned short* xs = (const unsigned short*)x;
    int f32 = 0;
    for (int i = t; i < 8192; i += 256) {
        unsigned e = (xs[i] >> 7) & 0xFF;   // bf16 exponent field
        if (e >= 134) f32 = 1;              // impossible for bf16 N(0,1) data
    }
    const int* eii = (const int*)ei;
    int odd = 0;                            // nonzero odd 32-bit slot -> int32 ids
    for (int i = t; i < 1024; i += 256)
        if (eii[2 * i + 1] != 0) odd = 1;
    if (f32) atomicOr(&flags[0], 1);
    if (odd) atomicOr(&flags[1], 1);
}

// ---- convert x and the four weight matrices to bf16 workspace ----------------
__global__ void convert(const void* __restrict__ x,
                        const void* __restrict__ wl1, const void* __restrict__ wr1,
                        const void* __restrict__ wl2, const void* __restrict__ wr2,
                        bf16* __restrict__ xb, bf16* __restrict__ wb,
                        const int* __restrict__ flags) {
    const int f32 = flags[0];
    const size_t XTOT = (size_t)N_NODES * 128;         // 6.4M
    const size_t TOT  = XTOT + 196608;
    for (size_t i = blockIdx.x * 256 + threadIdx.x; i < TOT; i += (size_t)gridDim.x * 256) {
        if (i < XTOT) {
            xb[i] = __float2bfloat16(loadF(x, i, f32));
        } else {
            size_t j = i - XTOT;
            const void* src; size_t off;
            if      (j <  32768) { src = wl1; off = j; }
            else if (j <  65536) { src = wr1; off = j - 32768; }
            else if (j < 131072) { src = wl2; off = j - 65536; }
            else                 { src = wr2; off = j - 131072; }
            wb[j] = __float2bfloat16(loadF(src, off, f32));
        }
    }
}

// ---- CSR build ---------------------------------------------------------------
__global__ void hist(const void* __restrict__ ei, int* __restrict__ counts,
                     const int* __restrict__ flags) {
    const int is32 = flags[1];
    int e = blockIdx.x * 256 + threadIdx.x;
    if (e >= E_TOT) return;
    int d = (e < E_RAW) ? loadI(ei, (size_t)E_RAW + e, is32) : (e - E_RAW);
    atomicAdd(&counts[d], 1);
}

__global__ void scan1(const int* __restrict__ counts, int* __restrict__ rp,
                      int* __restrict__ bsum) {
    __shared__ int sm[256];
    int b = blockIdx.x, t = threadIdx.x;
    int i = b * 256 + t;
    int v = (i < N_NODES) ? counts[i] : 0;
    sm[t] = v; __syncthreads();
    for (int off = 1; off < 256; off <<= 1) {
        int u = (t >= off) ? sm[t - off] : 0;
        __syncthreads();
        sm[t] += u;
        __syncthreads();
    }
    int incl = sm[t];
    if (i < N_NODES) rp[i] = incl - v;      // local exclusive
    if (t == 255) bsum[b] = incl;
}

__global__ void scan2(int* __restrict__ bsum) {
    __shared__ int sm[256];
    int t = threadIdx.x;
    int v = (t < NB_SCAN) ? bsum[t] : 0;
    sm[t] = v; __syncthreads();
    for (int off = 1; off < 256; off <<= 1) {
        int u = (t >= off) ? sm[t - off] : 0;
        __syncthreads();
        sm[t] += u;
        __syncthreads();
    }
    if (t < NB_SCAN) bsum[t] = sm[t] - v;   // exclusive
}

__global__ void scan3(int* __restrict__ rp, const int* __restrict__ bsum,
                      int* __restrict__ cursor) {
    int b = blockIdx.x, t = threadIdx.x;
    int i = b * 256 + t;
    if (i < N_NODES) {
        int r = rp[i] + bsum[b];
        rp[i] = r;
        cursor[i] = r;
    }
    if (i == 0) rp[N_NODES] = E_TOT;
}

__global__ void fill(const void* __restrict__ ei, int* __restrict__ cursor,
                     int* __restrict__ srcs, const int* __restrict__ flags) {
    const int is32 = flags[1];
    int e = blockIdx.x * 256 + threadIdx.x;
    if (e >= E_TOT) return;
    int s, d;
    if (e < E_RAW) { s = loadI(ei, e, is32); d = loadI(ei, (size_t)E_RAW + e, is32); }
    else           { s = d = e - E_RAW; }
    int pos = atomicAdd(&cursor[d], 1);
    srcs[pos] = s;
}

// ---- MFMA GEMM: C[M,256] = A[M,K] @ W[K,256], all bf16, fp32 accum -----------
// block = 256 thr (4 waves); tile 64(M) x 64(N); B pre-swizzled to frag order in LDS
__launch_bounds__(256)
__global__ void gemm_mfma(const bf16* __restrict__ A, const bf16* __restrict__ W,
                          bf16* __restrict__ C, int M, int K) {
    __shared__ __align__(16) short Bs[16384];   // up to K=256: (K/32)*4*64*8
    const int tid = threadIdx.x;
    const int bRow = blockIdx.x * 64;
    const int bCol = blockIdx.y * 64;
    const int nkb = K >> 5;

    // stage B swizzled: Bs[((kb*4+ct)*64+lane)*8+j] = W[(kb*32+(lane>>4)*8+j)*256 + bCol+ct*16+(lane&15)]
    const short* Ws = (const short*)W;
    for (int idx = tid; idx < nkb * 2048; idx += 256) {
        int kb   = idx >> 11;
        int r    = idx & 2047;
        int ct   = r >> 9;
        int lane = (r >> 3) & 63;
        int j    = r & 7;
        int k = kb * 32 + ((lane >> 4) << 3) + j;
        int n = bCol + ct * 16 + (lane & 15);
        Bs[idx] = Ws[k * 256 + n];
    }
    __syncthreads();

    const int w = tid >> 6, lane = tid & 63;
    const int q = lane >> 4, l16 = lane & 15;
    int rowA = bRow + w * 16 + l16;
    if (rowA >= M) rowA = M - 1;            // clamp; garbage rows store-guarded
    const bf16* aptr = A + (size_t)rowA * K + q * 8;

    f32x4 acc[4] = {f32x4{0,0,0,0}, f32x4{0,0,0,0}, f32x4{0,0,0,0}, f32x4{0,0,0,0}};
    for (int kb = 0; kb < nkb; ++kb) {
        bf16x8 af = *(const bf16x8*)(const void*)(aptr + kb * 32);
        const short* bb = &Bs[kb * 2048 + lane * 8];
#pragma unroll
        for (int ct = 0; ct < 4; ++ct) {
            bf16x8 bfr = *(const bf16x8*)(const void*)(bb + ct * 512);
            acc[ct] = __builtin_amdgcn_mfma_f32_16x16x32_bf16(af, bfr, acc[ct], 0, 0, 0);
        }
    }

    // C/D: col = lane&15, row = q*4 + reg (within the wave's 16-row strip)
#pragma unroll
    for (int ct = 0; ct < 4; ++ct) {
        int col = bCol + ct * 16 + l16;
#pragma unroll
        for (int r = 0; r < 4; ++r) {
            int row = bRow + w * 16 + q * 4 + r;
            if (row < M) C[(size_t)row * 256 + col] = __float2bfloat16(acc[ct][r]);
        }
    }
}

// ---- fused GATv2 attention + aggregation, one block per dst node -------------
// mode 1: out = ELU(agg + b) as bf16 [256/node]; mode 2: out = mean_heads(agg)+b
__launch_bounds__(256)
__global__ void fused_attn(const int* __restrict__ rp, const int* __restrict__ srcs,
                           const bf16* __restrict__ xl, const bf16* __restrict__ xr,
                           const void* __restrict__ att, const void* __restrict__ bias,
                           void* __restrict__ outp, int mode,
                           const int* __restrict__ flags) {
    const int f32 = flags[0];
    __shared__ float atts[256];
    __shared__ float red[256];
    const int d = blockIdx.x, c = threadIdx.x;
    atts[c] = loadF(att, c, f32);
    float xrv = __bfloat162float(xr[(size_t)d * 256 + c]);
    __syncthreads();
    const float attv = atts[c];

    const int start = rp[d], end = rp[d + 1];
    float num = 0.f, den = 0.f;
    int s_next = (start < end) ? srcs[start] : 0;
    for (int i = start; i < end; ++i) {
        int s = s_next;
        if (i + 1 < end) s_next = srcs[i + 1];
        float xlv = __bfloat162float(xl[(size_t)s * 256 + c]);
        float z = xlv + xrv;
        z = z > 0.f ? z : 0.2f * z;
        float p = z * attv;
        p += __shfl_xor(p, 16);             // reduce over the 32-lane head group
        p += __shfl_xor(p, 8);
        p += __shfl_xor(p, 4);
        p += __shfl_xor(p, 2);
        p += __shfl_xor(p, 1);
        float ew = __expf(p);
        num += ew * xlv;
        den += ew;
    }
    float v = num / (den + 1e-16f);

    if (mode == 1) {
        v += loadF(bias, c, f32);
        v = v > 0.f ? v : expm1f(v);
        ((bf16*)outp)[(size_t)d * 256 + c] = __float2bfloat16(v);
    } else {
        red[c] = v;
        __syncthreads();
        if (c < 32) {
            float s = 0.f;
#pragma unroll
            for (int h = 0; h < H_HEADS; ++h) s += red[h * 32 + c];
            float o = s * 0.125f + loadF(bias, c, f32);
            if (f32) ((float*)outp)[(size_t)d * 32 + c] = o;
            else     ((bf16*)outp)[(size_t)d * 32 + c] = __float2bfloat16(o);
        }
    }
}

extern "C" void kernel_launch(void* const* d_in, const int* in_sizes, int n_in,
                              void* d_out, int out_size, void* d_ws, size_t ws_size,
                              hipStream_t stream) {
    const void* x    = d_in[0];
    const void* ei   = d_in[1];
    const void* Wl1  = d_in[2];
    const void* Wr1  = d_in[3];
    const void* att1 = d_in[4];
    const void* b1   = d_in[5];
    const void* Wl2  = d_in[6];
    const void* Wr2  = d_in[7];
    const void* att2 = d_in[8];
    const void* b2   = d_in[9];

    // ---- workspace layout (256B-aligned regions) ----
    char* p = (char*)d_ws;
    auto take = [&](size_t bytes) { char* r = p; p += (bytes + 255) & ~(size_t)255; return r; };
    int*  flags  = (int*) take(64 * sizeof(int));
    bf16* xb     = (bf16*)take((size_t)N_NODES * 128 * sizeof(bf16));
    bf16* wb     = (bf16*)take(196608 * sizeof(bf16));
    bf16* xl     = (bf16*)take((size_t)N_NODES * F_DIM * sizeof(bf16));
    bf16* xr     = (bf16*)take((size_t)N_NODES * F_DIM * sizeof(bf16));
    bf16* h1     = (bf16*)take((size_t)N_NODES * F_DIM * sizeof(bf16));
    int*  rp     = (int*) take((N_NODES + 1) * sizeof(int));
    int*  cursor = (int*) take(N_NODES * sizeof(int));
    int*  counts = (int*) take(N_NODES * sizeof(int));
    int*  bsum   = (int*) take(256 * sizeof(int));
    int*  srcs   = (int*) take((size_t)E_TOT * sizeof(int));

    bf16* Wl1b = wb;
    bf16* Wr1b = wb + 32768;
    bf16* Wl2b = wb + 65536;
    bf16* Wr2b = wb + 131072;

    (void)hipMemsetAsync(flags, 0, 16, stream);
    (void)hipMemsetAsync(counts, 0, N_NODES * sizeof(int), stream);
    detect<<<1, 256, 0, stream>>>(x, ei, flags);

    // ---- CSR over dst (incl. self-loops) ----
    const int EB = (E_TOT + 255) / 256;
    hist <<<EB, 256, 0, stream>>>(ei, counts, flags);
    scan1<<<NB_SCAN, 256, 0, stream>>>(counts, rp, bsum);
    scan2<<<1, 256, 0, stream>>>(bsum);
    scan3<<<NB_SCAN, 256, 0, stream>>>(rp, bsum, cursor);
    fill <<<EB, 256, 0, stream>>>(ei, cursor, srcs, flags);

    // ---- bf16 conversions ----
    convert<<<2048, 256, 0, stream>>>(x, Wl1, Wr1, Wl2, Wr2, xb, wb, flags);

    dim3 ggrd((N_NODES + 63) / 64, 4);

    // ---- Layer 1 ----
    gemm_mfma<<<ggrd, 256, 0, stream>>>(xb, Wl1b, xl, N_NODES, 128);
    gemm_mfma<<<ggrd, 256, 0, stream>>>(xb, Wr1b, xr, N_NODES, 128);
    fused_attn<<<N_NODES, 256, 0, stream>>>(rp, srcs, xl, xr, att1, b1, h1, 1, flags);

    // ---- Layer 2 ----
    gemm_mfma<<<ggrd, 256, 0, stream>>>(h1, Wl2b, xl, N_NODES, 256);
    gemm_mfma<<<ggrd, 256, 0, stream>>>(h1, Wr2b, xr, N_NODES, 256);
    fused_attn<<<N_NODES, 256, 0, stream>>>(rp, srcs, xl, xr, att2, b2, d_out, 2, flags);
}

// Round 4
// 767.801 us; speedup vs baseline: 4.5575x; 1.2325x over previous
//
#include <hip/hip_runtime.h>
#include <hip/hip_bf16.h>

typedef __hip_bfloat16 bf16;
typedef __attribute__((ext_vector_type(8))) short bf16x8;   // 8 bf16 = 4 VGPRs
typedef __attribute__((ext_vector_type(4))) float f32x4;

#define N_NODES 50000
#define E_RAW   800000
#define E_TOT   850000      // E_RAW + N self-loops
#define H_HEADS 8
#define F_DIM   256
#define D_HEAD  32
#define NB_SCAN 196         // ceil(50000/256)

// ---- dtype-agnostic loads: flags[0]=1 -> floats are fp32; flags[1]=1 -> ints are int32
__device__ __forceinline__ float loadF(const void* p, size_t i, int f32) {
    return f32 ? ((const float*)p)[i] : __bfloat162float(((const bf16*)p)[i]);
}
__device__ __forceinline__ int loadI(const void* p, size_t i, int is32) {
    return is32 ? ((const int*)p)[i] : (int)((const long long*)p)[i];
}

// ---- detect input dtypes from data (deterministic; graph-capture safe) ----
__global__ void detect(const void* __restrict__ x, const void* __restrict__ ei,
                       int* __restrict__ flags) {
    int t = threadIdx.x;
    const unsigned short* xs = (const unsigned short*)x;
    int f32 = 0;
    for (int i = t; i < 8192; i += 256) {
        unsigned e = (xs[i] >> 7) & 0xFF;   // bf16 exponent field
        if (e >= 134) f32 = 1;              // impossible for bf16 N(0,1) data
    }
    const int* eii = (const int*)ei;
    int odd = 0;                            // nonzero odd 32-bit slot -> int32 ids
    for (int i = t; i < 1024; i += 256)
        if (eii[2 * i + 1] != 0) odd = 1;
    if (f32) atomicOr(&flags[0], 1);
    if (odd) atomicOr(&flags[1], 1);
}

// ---- convert x -> bf16; weights -> bf16 concat layout W1cat[128,512], W2cat[256,512]
__global__ void convert(const void* __restrict__ x,
                        const void* __restrict__ wl1, const void* __restrict__ wr1,
                        const void* __restrict__ wl2, const void* __restrict__ wr2,
                        bf16* __restrict__ xb, bf16* __restrict__ wb,
                        const int* __restrict__ flags) {
    const int f32 = flags[0];
    const size_t XTOT = (size_t)N_NODES * 128;         // 6.4M
    const size_t TOT  = XTOT + 196608;
    for (size_t i = blockIdx.x * 256 + threadIdx.x; i < TOT; i += (size_t)gridDim.x * 256) {
        if (i < XTOT) {
            xb[i] = __float2bfloat16(loadF(x, i, f32));
        } else {
            size_t j = i - XTOT;
            const void* src; size_t off, dst;
            if (j < 65536) {                           // layer-1 cat: [Wl1 | Wr1]
                int half = j >= 32768;
                off = j - (half ? 32768 : 0);
                src = half ? wr1 : wl1;
                size_t k = off >> 8, col = off & 255;
                dst = k * 512 + half * 256 + col;
            } else {                                   // layer-2 cat: [Wl2 | Wr2]
                size_t jj = j - 65536;
                int half = jj >= 65536;
                off = jj - (half ? 65536 : 0);
                src = half ? wr2 : wl2;
                size_t k = off >> 8, col = off & 255;
                dst = 65536 + k * 512 + half * 256 + col;
            }
            wb[dst] = __float2bfloat16(loadF(src, off, f32));
        }
    }
}

// ---- CSR build ---------------------------------------------------------------
__global__ void hist(const void* __restrict__ ei, int* __restrict__ counts,
                     const int* __restrict__ flags) {
    const int is32 = flags[1];
    int e = blockIdx.x * 256 + threadIdx.x;
    if (e >= E_TOT) return;
    int d = (e < E_RAW) ? loadI(ei, (size_t)E_RAW + e, is32) : (e - E_RAW);
    atomicAdd(&counts[d], 1);
}

__global__ void scan1(const int* __restrict__ counts, int* __restrict__ rp,
                      int* __restrict__ bsum) {
    __shared__ int sm[256];
    int b = blockIdx.x, t = threadIdx.x;
    int i = b * 256 + t;
    int v = (i < N_NODES) ? counts[i] : 0;
    sm[t] = v; __syncthreads();
    for (int off = 1; off < 256; off <<= 1) {
        int u = (t >= off) ? sm[t - off] : 0;
        __syncthreads();
        sm[t] += u;
        __syncthreads();
    }
    int incl = sm[t];
    if (i < N_NODES) rp[i] = incl - v;      // local exclusive
    if (t == 255) bsum[b] = incl;
}

__global__ void scan2(int* __restrict__ bsum) {
    __shared__ int sm[256];
    int t = threadIdx.x;
    int v = (t < NB_SCAN) ? bsum[t] : 0;
    sm[t] = v; __syncthreads();
    for (int off = 1; off < 256; off <<= 1) {
        int u = (t >= off) ? sm[t - off] : 0;
        __syncthreads();
        sm[t] += u;
        __syncthreads();
    }
    if (t < NB_SCAN) bsum[t] = sm[t] - v;   // exclusive
}

__global__ void scan3(int* __restrict__ rp, const int* __restrict__ bsum,
                      int* __restrict__ cursor) {
    int b = blockIdx.x, t = threadIdx.x;
    int i = b * 256 + t;
    if (i < N_NODES) {
        int r = rp[i] + bsum[b];
        rp[i] = r;
        cursor[i] = r;
    }
    if (i == 0) rp[N_NODES] = E_TOT;
}

__global__ void fill(const void* __restrict__ ei, int* __restrict__ cursor,
                     int* __restrict__ srcs, const int* __restrict__ flags) {
    const int is32 = flags[1];
    int e = blockIdx.x * 256 + threadIdx.x;
    if (e >= E_TOT) return;
    int s, d;
    if (e < E_RAW) { s = loadI(ei, e, is32); d = loadI(ei, (size_t)E_RAW + e, is32); }
    else           { s = d = e - E_RAW; }
    int pos = atomicAdd(&cursor[d], 1);
    srcs[pos] = s;
}

// ---- MFMA dual-GEMM: [Cl|Cr][M,512] = A[M,K] @ Wcat[K,512], bf16 in/out ------
// block = 256 thr (4 waves); tile 64(M) x 64(N); B pre-swizzled to frag order in LDS
__launch_bounds__(256)
__global__ void gemm_mfma(const bf16* __restrict__ A, const bf16* __restrict__ W,
                          bf16* __restrict__ Cl, bf16* __restrict__ Cr,
                          int M, int K) {
    __shared__ __align__(16) short Bs[16384];   // up to K=256: (K/32)*4*64*8
    const int tid = threadIdx.x;
    const int bRow = blockIdx.x * 64;
    const int bCol = blockIdx.y * 64;           // 0..511 over [Wl|Wr]
    const int nkb = K >> 5;

    // stage B swizzled: Bs[((kb*4+ct)*64+lane)*8+j] = W[(kb*32+(lane>>4)*8+j)*512 + bCol+ct*16+(lane&15)]
    const short* Ws = (const short*)W;
    for (int idx = tid; idx < nkb * 2048; idx += 256) {
        int kb   = idx >> 11;
        int r    = idx & 2047;
        int ct   = r >> 9;
        int lane = (r >> 3) & 63;
        int j    = r & 7;
        int k = kb * 32 + ((lane >> 4) << 3) + j;
        int n = bCol + ct * 16 + (lane & 15);
        Bs[idx] = Ws[k * 512 + n];
    }
    __syncthreads();

    const int w = tid >> 6, lane = tid & 63;
    const int q = lane >> 4, l16 = lane & 15;
    int rowA = bRow + w * 16 + l16;
    if (rowA >= M) rowA = M - 1;            // clamp; garbage rows store-guarded
    const bf16* aptr = A + (size_t)rowA * K + q * 8;

    f32x4 acc[4] = {f32x4{0,0,0,0}, f32x4{0,0,0,0}, f32x4{0,0,0,0}, f32x4{0,0,0,0}};
    for (int kb = 0; kb < nkb; ++kb) {
        bf16x8 af = *(const bf16x8*)(const void*)(aptr + kb * 32);
        const short* bb = &Bs[kb * 2048 + lane * 8];
#pragma unroll
        for (int ct = 0; ct < 4; ++ct) {
            bf16x8 bfr = *(const bf16x8*)(const void*)(bb + ct * 512);
            acc[ct] = __builtin_amdgcn_mfma_f32_16x16x32_bf16(af, bfr, acc[ct], 0, 0, 0);
        }
    }

    bf16* C    = (bCol < 256) ? Cl : Cr;
    int   cOff = (bCol < 256) ? bCol : bCol - 256;
    // C/D: col = lane&15, row = q*4 + reg (within the wave's 16-row strip)
#pragma unroll
    for (int ct = 0; ct < 4; ++ct) {
        int col = cOff + ct * 16 + l16;
#pragma unroll
        for (int r = 0; r < 4; ++r) {
            int row = bRow + w * 16 + q * 4 + r;
            if (row < M) C[(size_t)row * 256 + col] = __float2bfloat16(acc[ct][r]);
        }
    }
}

// ---- fused GATv2 attention + aggregation, one block per dst node -------------
// mode 1: out = ELU(agg + b) as bf16 [256/node]; mode 2: out = mean_heads(agg)+b
#define HRED(p) { p += __shfl_xor(p, 16); p += __shfl_xor(p, 8); \
                  p += __shfl_xor(p, 4);  p += __shfl_xor(p, 2); p += __shfl_xor(p, 1); }
__launch_bounds__(256)
__global__ void fused_attn(const int* __restrict__ rp, const int* __restrict__ srcs,
                           const bf16* __restrict__ xl, const bf16* __restrict__ xr,
                           const void* __restrict__ att, const void* __restrict__ bias,
                           void* __restrict__ outp, int mode,
                           const int* __restrict__ flags) {
    const int f32 = flags[0];
    __shared__ float atts[256];
    __shared__ float red[256];
    const int d = blockIdx.x, c = threadIdx.x;
    atts[c] = loadF(att, c, f32);
    float xrv = __bfloat162float(xr[(size_t)d * 256 + c]);
    __syncthreads();
    const float attv = atts[c];

    const int start = rp[d], end = rp[d + 1];
    float num = 0.f, den = 0.f;
    int i = start;
    // 4-way unrolled: 4 independent load->shuffle-tree->exp chains in flight
    for (; i + 3 < end; i += 4) {
        int s0 = srcs[i], s1 = srcs[i + 1], s2 = srcs[i + 2], s3 = srcs[i + 3];
        float x0 = __bfloat162float(xl[(size_t)s0 * 256 + c]);
        float x1 = __bfloat162float(xl[(size_t)s1 * 256 + c]);
        float x2 = __bfloat162float(xl[(size_t)s2 * 256 + c]);
        float x3 = __bfloat162float(xl[(size_t)s3 * 256 + c]);
        float z0 = x0 + xrv; z0 = z0 > 0.f ? z0 : 0.2f * z0;
        float z1 = x1 + xrv; z1 = z1 > 0.f ? z1 : 0.2f * z1;
        float z2 = x2 + xrv; z2 = z2 > 0.f ? z2 : 0.2f * z2;
        float z3 = x3 + xrv; z3 = z3 > 0.f ? z3 : 0.2f * z3;
        float p0 = z0 * attv, p1 = z1 * attv, p2 = z2 * attv, p3 = z3 * attv;
        HRED(p0); HRED(p1); HRED(p2); HRED(p3);
        float e0 = __expf(p0), e1 = __expf(p1), e2 = __expf(p2), e3 = __expf(p3);
        num += e0 * x0; num += e1 * x1; num += e2 * x2; num += e3 * x3;
        den += (e0 + e1) + (e2 + e3);
    }
    for (; i < end; ++i) {
        int s = srcs[i];
        float xlv = __bfloat162float(xl[(size_t)s * 256 + c]);
        float z = xlv + xrv;
        z = z > 0.f ? z : 0.2f * z;
        float p = z * attv;
        HRED(p);
        float ew = __expf(p);
        num += ew * xlv;
        den += ew;
    }
    float v = num / (den + 1e-16f);

    if (mode == 1) {
        v += loadF(bias, c, f32);
        v = v > 0.f ? v : expm1f(v);
        ((bf16*)outp)[(size_t)d * 256 + c] = __float2bfloat16(v);
    } else {
        red[c] = v;
        __syncthreads();
        if (c < 32) {
            float s = 0.f;
#pragma unroll
            for (int h = 0; h < H_HEADS; ++h) s += red[h * 32 + c];
            float o = s * 0.125f + loadF(bias, c, f32);
            if (f32) ((float*)outp)[(size_t)d * 32 + c] = o;
            else     ((bf16*)outp)[(size_t)d * 32 + c] = __float2bfloat16(o);
        }
    }
}

extern "C" void kernel_launch(void* const* d_in, const int* in_sizes, int n_in,
                              void* d_out, int out_size, void* d_ws, size_t ws_size,
                              hipStream_t stream) {
    const void* x    = d_in[0];
    const void* ei   = d_in[1];
    const void* Wl1  = d_in[2];
    const void* Wr1  = d_in[3];
    const void* att1 = d_in[4];
    const void* b1   = d_in[5];
    const void* Wl2  = d_in[6];
    const void* Wr2  = d_in[7];
    const void* att2 = d_in[8];
    const void* b2   = d_in[9];

    // ---- workspace layout (256B-aligned regions) ----
    char* p = (char*)d_ws;
    auto take = [&](size_t bytes) { char* r = p; p += (bytes + 255) & ~(size_t)255; return r; };
    int*  flags  = (int*) take(64 * sizeof(int));
    bf16* xb     = (bf16*)take((size_t)N_NODES * 128 * sizeof(bf16));
    bf16* wb     = (bf16*)take(196608 * sizeof(bf16));
    bf16* xl     = (bf16*)take((size_t)N_NODES * F_DIM * sizeof(bf16));
    bf16* xr     = (bf16*)take((size_t)N_NODES * F_DIM * sizeof(bf16));
    bf16* h1     = (bf16*)take((size_t)N_NODES * F_DIM * sizeof(bf16));
    int*  rp     = (int*) take((N_NODES + 1) * sizeof(int));
    int*  cursor = (int*) take(N_NODES * sizeof(int));
    int*  counts = (int*) take(N_NODES * sizeof(int));
    int*  bsum   = (int*) take(256 * sizeof(int));
    int*  srcs   = (int*) take((size_t)E_TOT * sizeof(int));

    bf16* W1cat = wb;           // [128,512] = [Wl1|Wr1]
    bf16* W2cat = wb + 65536;   // [256,512] = [Wl2|Wr2]

    (void)hipMemsetAsync(flags, 0, 16, stream);
    (void)hipMemsetAsync(counts, 0, N_NODES * sizeof(int), stream);
    detect<<<1, 256, 0, stream>>>(x, ei, flags);

    // ---- CSR over dst (incl. self-loops) ----
    const int EB = (E_TOT + 255) / 256;
    hist <<<EB, 256, 0, stream>>>(ei, counts, flags);
    scan1<<<NB_SCAN, 256, 0, stream>>>(counts, rp, bsum);
    scan2<<<1, 256, 0, stream>>>(bsum);
    scan3<<<NB_SCAN, 256, 0, stream>>>(rp, bsum, cursor);
    fill <<<EB, 256, 0, stream>>>(ei, cursor, srcs, flags);

    // ---- bf16 conversions ----
    convert<<<2048, 256, 0, stream>>>(x, Wl1, Wr1, Wl2, Wr2, xb, wb, flags);

    dim3 ggrd((N_NODES + 63) / 64, 8);

    // ---- Layer 1 ----
    gemm_mfma<<<ggrd, 256, 0, stream>>>(xb, W1cat, xl, xr, N_NODES, 128);
    fused_attn<<<N_NODES, 256, 0, stream>>>(rp, srcs, xl, xr, att1, b1, h1, 1, flags);

    // ---- Layer 2 ----
    gemm_mfma<<<ggrd, 256, 0, stream>>>(h1, W2cat, xl, xr, N_NODES, 256);
    fused_attn<<<N_NODES, 256, 0, stream>>>(rp, srcs, xl, xr, att2, b2, d_out, 2, flags);
}

// Round 5
// 631.442 us; speedup vs baseline: 5.5417x; 1.2159x over previous
//
#include <hip/hip_runtime.h>
#include <hip/hip_bf16.h>

typedef __hip_bfloat16 bf16;
typedef __attribute__((ext_vector_type(8))) short bf16x8;          // 8 bf16 = 4 VGPRs
typedef __attribute__((ext_vector_type(8))) unsigned short ushort8;
typedef __attribute__((ext_vector_type(4))) float f32x4;

#define N_NODES 50000
#define E_RAW   800000
#define E_TOT   850000      // E_RAW + N self-loops
#define H_HEADS 8
#define F_DIM   256
#define NB_SCAN 196         // ceil(50000/256)

// ---- dtype-agnostic loads: flags[0]=1 -> floats are fp32; flags[1]=1 -> ints are int32
__device__ __forceinline__ float loadF(const void* p, size_t i, int f32) {
    return f32 ? ((const float*)p)[i] : __bfloat162float(((const bf16*)p)[i]);
}
__device__ __forceinline__ int loadI(const void* p, size_t i, int is32) {
    return is32 ? ((const int*)p)[i] : (int)((const long long*)p)[i];
}
__device__ __forceinline__ float bfu(unsigned short u) {
    return __uint_as_float((unsigned)u << 16);
}

// ---- detect input dtypes from data (deterministic; graph-capture safe) ----
__global__ void detect(const void* __restrict__ x, const void* __restrict__ ei,
                       int* __restrict__ flags) {
    int t = threadIdx.x;
    const unsigned short* xs = (const unsigned short*)x;
    int f32 = 0;
    for (int i = t; i < 8192; i += 256) {
        unsigned e = (xs[i] >> 7) & 0xFF;   // bf16 exponent field
        if (e >= 134) f32 = 1;              // impossible for bf16 N(0,1) data
    }
    const int* eii = (const int*)ei;
    int odd = 0;                            // nonzero odd 32-bit slot -> int32 ids
    for (int i = t; i < 1024; i += 256)
        if (eii[2 * i + 1] != 0) odd = 1;
    if (f32) atomicOr(&flags[0], 1);
    if (odd) atomicOr(&flags[1], 1);
}

// ---- convert x -> bf16; weights -> bf16 in MFMA B-fragment ("swizzled") order.
// Swizzle for a [K,512] cat-matrix: element (k,n) -> ((kb*32+ctg)*64+lane)*8+j
// with kb=k>>5, j=k&7, lane=((k>>3)&3)*16+(n&15), ctg=n>>4.
__global__ void convert(const void* __restrict__ x,
                        const void* __restrict__ wl1, const void* __restrict__ wr1,
                        const void* __restrict__ wl2, const void* __restrict__ wr2,
                        bf16* __restrict__ xb, bf16* __restrict__ wb,
                        const int* __restrict__ flags) {
    const int f32 = flags[0];
    const size_t XTOT = (size_t)N_NODES * 128;         // 6.4M
    const size_t TOT  = XTOT + 196608;
    for (size_t i = blockIdx.x * 256 + threadIdx.x; i < TOT; i += (size_t)gridDim.x * 256) {
        if (i < XTOT) {
            xb[i] = __float2bfloat16(loadF(x, i, f32));
        } else {
            size_t j = i - XTOT;
            const void* src; size_t off, base;
            int k, n;
            if (j < 65536) {                           // layer-1 cat [Wl1|Wr1], K=128
                int half = j >= 32768;
                off = j - (size_t)half * 32768;
                src = half ? wr1 : wl1;
                k = (int)(off >> 8); n = half * 256 + (int)(off & 255);
                base = 0;
            } else {                                   // layer-2 cat [Wl2|Wr2], K=256
                size_t jj = j - 65536;
                int half = jj >= 65536;
                off = jj - (size_t)half * 65536;
                src = half ? wr2 : wl2;
                k = (int)(off >> 8); n = half * 256 + (int)(off & 255);
                base = 65536;
            }
            int kb = k >> 5, jo = k & 7;
            int lane = ((k >> 3) & 3) * 16 + (n & 15);
            int ctg = n >> 4;
            size_t dst = base + (((size_t)(kb * 32 + ctg) * 64 + lane) * 8 + jo);
            wb[dst] = __float2bfloat16(loadF(src, off, f32));
        }
    }
}

// ---- CSR build ---------------------------------------------------------------
__global__ void hist(const void* __restrict__ ei, int* __restrict__ counts,
                     const int* __restrict__ flags) {
    const int is32 = flags[1];
    int e = blockIdx.x * 256 + threadIdx.x;
    if (e >= E_TOT) return;
    int d = (e < E_RAW) ? loadI(ei, (size_t)E_RAW + e, is32) : (e - E_RAW);
    atomicAdd(&counts[d], 1);
}

__global__ void scan1(const int* __restrict__ counts, int* __restrict__ rp,
                      int* __restrict__ bsum) {
    __shared__ int sm[256];
    int b = blockIdx.x, t = threadIdx.x;
    int i = b * 256 + t;
    int v = (i < N_NODES) ? counts[i] : 0;
    sm[t] = v; __syncthreads();
    for (int off = 1; off < 256; off <<= 1) {
        int u = (t >= off) ? sm[t - off] : 0;
        __syncthreads();
        sm[t] += u;
        __syncthreads();
    }
    int incl = sm[t];
    if (i < N_NODES) rp[i] = incl - v;      // local exclusive
    if (t == 255) bsum[b] = incl;
}

__global__ void scan2(int* __restrict__ bsum) {
    __shared__ int sm[256];
    int t = threadIdx.x;
    int v = (t < NB_SCAN) ? bsum[t] : 0;
    sm[t] = v; __syncthreads();
    for (int off = 1; off < 256; off <<= 1) {
        int u = (t >= off) ? sm[t - off] : 0;
        __syncthreads();
        sm[t] += u;
        __syncthreads();
    }
    if (t < NB_SCAN) bsum[t] = sm[t] - v;   // exclusive
}

__global__ void scan3(int* __restrict__ rp, const int* __restrict__ bsum,
                      int* __restrict__ cursor) {
    int b = blockIdx.x, t = threadIdx.x;
    int i = b * 256 + t;
    if (i < N_NODES) {
        int r = rp[i] + bsum[b];
        rp[i] = r;
        cursor[i] = r;
    }
    if (i == 0) rp[N_NODES] = E_TOT;
}

__global__ void fill(const void* __restrict__ ei, int* __restrict__ cursor,
                     int* __restrict__ srcs, const int* __restrict__ flags) {
    const int is32 = flags[1];
    int e = blockIdx.x * 256 + threadIdx.x;
    if (e >= E_TOT) return;
    int s, d;
    if (e < E_RAW) { s = loadI(ei, e, is32); d = loadI(ei, (size_t)E_RAW + e, is32); }
    else           { s = d = e - E_RAW; }
    int pos = atomicAdd(&cursor[d], 1);
    srcs[pos] = s;
}

// ---- MFMA dual-GEMM, LDS-free: [Cl|Cr][M,512] = A[M,K] @ Wsw[K,512] ----------
// W pre-swizzled to B-frag order; each wave loads its own frags (1KB coalesced).
__launch_bounds__(256)
__global__ void gemm_mfma(const bf16* __restrict__ A, const bf16* __restrict__ Wsw,
                          bf16* __restrict__ Cl, bf16* __restrict__ Cr,
                          int M, int K) {
    const int tid = threadIdx.x;
    const int w = tid >> 6, lane = tid & 63, q = lane >> 4, l16 = lane & 15;
    const int bRow = blockIdx.x * 64;
    const int ctgBase = blockIdx.y * 16;      // 256 cols per block (16 col-groups)
    int rowA = bRow + w * 16 + l16;
    if (rowA >= M) rowA = M - 1;              // clamp; stores are guarded
    const short* Ap = (const short*)A + (size_t)rowA * K + q * 8;
    const short* Wp = (const short*)Wsw;
    const int nkb = K >> 5;
    f32x4 acc[16] = {};
    for (int kb = 0; kb < nkb; ++kb) {
        bf16x8 af = *(const bf16x8*)(Ap + kb * 32);
        const short* bb = Wp + ((size_t)(kb * 32 + ctgBase) * 64 + lane) * 8;
#pragma unroll
        for (int ct = 0; ct < 16; ++ct) {
            bf16x8 bfr = *(const bf16x8*)(bb + ct * 512);
            acc[ct] = __builtin_amdgcn_mfma_f32_16x16x32_bf16(af, bfr, acc[ct], 0, 0, 0);
        }
    }
    bf16* C = ctgBase ? Cr : Cl;              // y=0 -> cols 0..255 (Wl half)
#pragma unroll
    for (int ct = 0; ct < 16; ++ct) {
        int col = ct * 16 + l16;
#pragma unroll
        for (int r = 0; r < 4; ++r) {
            int row = bRow + w * 16 + q * 4 + r;
            if (row < M) C[(size_t)row * 256 + col] = __float2bfloat16(acc[ct][r]);
        }
    }
}

// ---- fused GATv2 attention + aggregation, one block per dst node -------------
// Two-phase, chunked (32 edges): phase 1 = one thread per (edge,head) computes
// the logit serially (no shuffles) and stages the gathered xl row to LDS;
// phase 2 = lean weighted accumulation from LDS.
// mode 1: out = ELU(agg + b) bf16 [256/node]; mode 2: out = mean_heads(agg) + b
__launch_bounds__(256)
__global__ void fused_attn(const int* __restrict__ rp, const int* __restrict__ srcs,
                           const bf16* __restrict__ xl, const bf16* __restrict__ xr,
                           const void* __restrict__ att, const void* __restrict__ bias,
                           void* __restrict__ outp, int mode,
                           const int* __restrict__ flags) {
    const int f32 = flags[0];
    __shared__ float att_sw[8 * 34];          // stride 34: conflict-free per-h float2
    __shared__ float xr_sw[8 * 34];
    __shared__ unsigned short xls[32 * 256];  // staged xl rows (bf16 bits)
    __shared__ float ews[32 * 8];             // exp(logit) per (edge,head)
    __shared__ int   srcs_s[32];
    __shared__ float dred[256];
    __shared__ float dfin[8];
    __shared__ float red[512];

    const int d = blockIdx.x, tid = threadIdx.x;
    {   // stage att + xr row (f32, swizzled stride-34)
        int h = tid >> 5, j = tid & 31;
        att_sw[h * 34 + j] = loadF(att, tid, f32);
        xr_sw[h * 34 + j]  = bfu(((const unsigned short*)xr)[(size_t)d * 256 + tid]);
    }
    const int start = rp[d], end = rp[d + 1];
    const int ec = tid >> 3, hh = tid & 7;            // phase-1 role
    const float2* xr2 = (const float2*)(xr_sw + hh * 34);
    const float2* at2 = (const float2*)(att_sw + hh * 34);
    const int half = tid >> 7, pp = tid & 127;        // phase-2 role (2 dims/thread)
    float mden = 0.f;
    float2 nacc = {0.f, 0.f};

    for (int base = start; base < end; base += 32) {
        int rem = end - base; if (rem > 32) rem = 32;
        if (tid < 32) srcs_s[tid] = srcs[base + tid]; // srcs padded by 64 ints
        __syncthreads();
        // ---- phase 1: logits ----
        bool on = ec < rem;
        int s = srcs_s[on ? ec : 0];
        const ushort8* xp = (const ushort8*)((const unsigned short*)xl + (size_t)s * 256 + hh * 32);
        ushort8 r0 = xp[0], r1 = xp[1], r2 = xp[2], r3 = xp[3];
        ushort8* xst = (ushort8*)(xls + ec * 256 + hh * 32);
        xst[0] = r0; xst[1] = r1; xst[2] = r2; xst[3] = r3;
        float p = 0.f;
        ushort8 rr[4] = {r0, r1, r2, r3};
#pragma unroll
        for (int qq = 0; qq < 4; ++qq) {
#pragma unroll
            for (int j2 = 0; j2 < 4; ++j2) {
                float  xa = bfu(rr[qq][j2 * 2]);
                float  xb = bfu(rr[qq][j2 * 2 + 1]);
                float2 rv = xr2[qq * 4 + j2];
                float2 av = at2[qq * 4 + j2];
                float z0 = xa + rv.x; z0 = fmaxf(z0, 0.2f * z0);
                float z1 = xb + rv.y; z1 = fmaxf(z1, 0.2f * z1);
                p = fmaf(z0, av.x, p);
                p = fmaf(z1, av.y, p);
            }
        }
        float e = on ? __expf(p) : 0.f;
        ews[ec * 8 + hh] = e;
        mden += e;
        __syncthreads();
        // ---- phase 2: weighted accumulation (waves split by edge parity) ----
        for (int e2 = half; e2 < rem; e2 += 2) {
            float wv = ews[e2 * 8 + (pp >> 4)];
            unsigned xv = *(const unsigned*)(xls + e2 * 256 + pp * 2);
            nacc.x = fmaf(wv, bfu((unsigned short)(xv & 0xFFFF)), nacc.x);
            nacc.y = fmaf(wv, bfu((unsigned short)(xv >> 16)),    nacc.y);
        }
        __syncthreads();
    }
    // ---- denominator reduce ----
    dred[tid] = mden;
    __syncthreads();
    if (tid < 8) {
        float sden = 0.f;
#pragma unroll
        for (int i = 0; i < 32; ++i) sden += dred[i * 8 + tid];
        dfin[tid] = sden + 1e-16f;
    }
    red[half * 256 + pp * 2]     = nacc.x;
    red[half * 256 + pp * 2 + 1] = nacc.y;
    __syncthreads();
    float num = red[tid] + red[256 + tid];
    float v = num / dfin[tid >> 5];

    if (mode == 1) {
        v += loadF(bias, tid, f32);
        v = v > 0.f ? v : expm1f(v);
        ((bf16*)outp)[(size_t)d * 256 + tid] = __float2bfloat16(v);
    } else {
        __syncthreads();
        red[tid] = v;
        __syncthreads();
        if (tid < 32) {
            float s = 0.f;
#pragma unroll
            for (int h = 0; h < H_HEADS; ++h) s += red[h * 32 + tid];
            float o = s * 0.125f + loadF(bias, tid, f32);
            if (f32) ((float*)outp)[(size_t)d * 32 + tid] = o;
            else     ((bf16*)outp)[(size_t)d * 32 + tid] = __float2bfloat16(o);
        }
    }
}

extern "C" void kernel_launch(void* const* d_in, const int* in_sizes, int n_in,
                              void* d_out, int out_size, void* d_ws, size_t ws_size,
                              hipStream_t stream) {
    const void* x    = d_in[0];
    const void* ei   = d_in[1];
    const void* Wl1  = d_in[2];
    const void* Wr1  = d_in[3];
    const void* att1 = d_in[4];
    const void* b1   = d_in[5];
    const void* Wl2  = d_in[6];
    const void* Wr2  = d_in[7];
    const void* att2 = d_in[8];
    const void* b2   = d_in[9];

    // ---- workspace layout (256B-aligned regions) ----
    char* p = (char*)d_ws;
    auto take = [&](size_t bytes) { char* r = p; p += (bytes + 255) & ~(size_t)255; return r; };
    int*  flags  = (int*) take(64 * sizeof(int));
    bf16* xb     = (bf16*)take((size_t)N_NODES * 128 * sizeof(bf16));
    bf16* wb     = (bf16*)take(196608 * sizeof(bf16));
    bf16* xl     = (bf16*)take((size_t)N_NODES * F_DIM * sizeof(bf16));
    bf16* xr     = (bf16*)take((size_t)N_NODES * F_DIM * sizeof(bf16));
    bf16* h1     = (bf16*)take((size_t)N_NODES * F_DIM * sizeof(bf16));
    int*  rp     = (int*) take((N_NODES + 1) * sizeof(int));
    int*  cursor = (int*) take(N_NODES * sizeof(int));
    int*  counts = (int*) take(N_NODES * sizeof(int));
    int*  bsum   = (int*) take(256 * sizeof(int));
    int*  srcs   = (int*) take(((size_t)E_TOT + 64) * sizeof(int)); // +pad (chunk over-read)

    bf16* W1sw = wb;            // [128,512] = [Wl1|Wr1], B-frag order
    bf16* W2sw = wb + 65536;    // [256,512] = [Wl2|Wr2], B-frag order

    (void)hipMemsetAsync(flags, 0, 16, stream);
    (void)hipMemsetAsync(counts, 0, N_NODES * sizeof(int), stream);
    detect<<<1, 256, 0, stream>>>(x, ei, flags);

    // ---- CSR over dst (incl. self-loops) ----
    const int EB = (E_TOT + 255) / 256;
    hist <<<EB, 256, 0, stream>>>(ei, counts, flags);
    scan1<<<NB_SCAN, 256, 0, stream>>>(counts, rp, bsum);
    scan2<<<1, 256, 0, stream>>>(bsum);
    scan3<<<NB_SCAN, 256, 0, stream>>>(rp, bsum, cursor);
    fill <<<EB, 256, 0, stream>>>(ei, cursor, srcs, flags);

    // ---- bf16 conversions + W swizzle ----
    convert<<<2048, 256, 0, stream>>>(x, Wl1, Wr1, Wl2, Wr2, xb, wb, flags);

    dim3 ggrd((N_NODES + 63) / 64, 2);

    // ---- Layer 1 ----
    gemm_mfma<<<ggrd, 256, 0, stream>>>(xb, W1sw, xl, xr, N_NODES, 128);
    fused_attn<<<N_NODES, 256, 0, stream>>>(rp, srcs, xl, xr, att1, b1, h1, 1, flags);

    // ---- Layer 2 ----
    gemm_mfma<<<ggrd, 256, 0, stream>>>(h1, W2sw, xl, xr, N_NODES, 256);
    fused_attn<<<N_NODES, 256, 0, stream>>>(rp, srcs, xl, xr, att2, b2, d_out, 2, flags);
}